// Round 1
// baseline (326.373 us; speedup 1.0000x reference)
//
#include <hip/hip_runtime.h>
#include <hip/hip_bf16.h>
#include <cstdint>
#include <cstddef>

// Problem dims (fixed by the reference): B=64, S=512, D=768, C=512
#define BB 64
#define SS 512
#define DD 768
#define CC 512

typedef __attribute__((ext_vector_type(8))) short short8;
typedef __attribute__((ext_vector_type(4))) float f32x4;

// float -> bf16 bits, round-to-nearest-even
static __device__ __forceinline__ unsigned short f2bf(float f) {
  union { float f; unsigned u; } v; v.f = f;
  unsigned u = v.u;
  u += 0x7FFFu + ((u >> 16) & 1u);
  return (unsigned short)(u >> 16);
}

// ---------------------------------------------------------------------------
// Kernel 1: normalize label embeddings (fp32) -> bf16 rows in ws.
// grid = C blocks x 256 threads; each thread owns 3 elements of the row.
// ---------------------------------------------------------------------------
__global__ __launch_bounds__(256) void k_label_norm(const float* __restrict__ L,
                                                    unsigned short* __restrict__ Lnb) {
  const int c = blockIdx.x;
  const int tid = threadIdx.x;
  const float* row = L + (size_t)c * DD;
  float v[3];
  float s = 0.f;
#pragma unroll
  for (int k = 0; k < 3; k++) { v[k] = row[tid + 256 * k]; s += v[k] * v[k]; }
#pragma unroll
  for (int o = 32; o > 0; o >>= 1) s += __shfl_xor(s, o, 64);
  __shared__ float wsum[4];
  if ((tid & 63) == 0) wsum[tid >> 6] = s;
  __syncthreads();
  const float tot = wsum[0] + wsum[1] + wsum[2] + wsum[3];
  const float inv = 1.f / fmaxf(sqrtf(tot), 1e-8f);
  unsigned short* orow = Lnb + (size_t)c * DD;
#pragma unroll
  for (int k = 0; k < 3; k++) orow[tid + 256 * k] = f2bf(v[k] * inv);
}

// ---------------------------------------------------------------------------
// Kernel 2 (the big one): m[b,s] = max_c dot(V[b,s,:], Ln[c,:]) / max(||V||,eps)
// Grid 512 blocks x 256 threads (4 waves). Wave owns 16 tokens; its 24
// A-fragments (16x32 bf16 each) live in registers; V is read exactly once.
// Per class-chunk (16 classes), the block stages all 768 K of Ln rows in LDS
// (row stride 776 bf16 -> only 2-way bank aliasing, free on CDNA4), runs
// 24 MFMAs, folds running max. Epilogue: cross-lane max + norm divide.
// ---------------------------------------------------------------------------
__global__ __launch_bounds__(256) void k_sims_max(const float* __restrict__ V,
                                                  const unsigned short* __restrict__ Lnb,
                                                  float* __restrict__ m_out) {
  const int tid = threadIdx.x;
  const int wave = tid >> 6;
  const int lane = tid & 63;
  const int q = lane >> 4;    // quad 0..3
  const int mr = lane & 15;   // row (token) for A, col (class) for B
  const int64_t tokBase = (int64_t)blockIdx.x * 64 + wave * 16;
  const float* arow = V + (tokBase + mr) * DD + q * 8;

  short8 afrag[24];
  float nrm2 = 0.f;
#pragma unroll
  for (int kc = 0; kc < 24; kc++) {
    const float4* p = (const float4*)(arow + kc * 32);
    const float4 x = p[0];
    const float4 y = p[1];
    short8 a;
    a[0] = (short)f2bf(x.x); a[1] = (short)f2bf(x.y);
    a[2] = (short)f2bf(x.z); a[3] = (short)f2bf(x.w);
    a[4] = (short)f2bf(y.x); a[5] = (short)f2bf(y.y);
    a[6] = (short)f2bf(y.z); a[7] = (short)f2bf(y.w);
    afrag[kc] = a;
    nrm2 += x.x * x.x + x.y * x.y + x.z * x.z + x.w * x.w;
    nrm2 += y.x * y.x + y.y * y.y + y.z * y.z + y.w * y.w;
  }
  // lanes {m, m+16, m+32, m+48} each hold 1/4 of token m's sum of squares
  nrm2 += __shfl_xor(nrm2, 16, 64);
  nrm2 += __shfl_xor(nrm2, 32, 64);

  __shared__ unsigned short Bs[16][776];  // +8 pad: 1552B stride -> 2-way only
  __shared__ float nrmS[4][16];
  if (q == 0) nrmS[wave][mr] = nrm2;  // same-wave write/read, lgkmcnt-ordered

  f32x4 vmax = {-3e38f, -3e38f, -3e38f, -3e38f};
  for (int cc = 0; cc < 32; cc++) {
    __syncthreads();
    // cooperative load: 16 classes x 768 bf16 = 24 KB, 16B per thread-iter
    const short8* src = (const short8*)(Lnb + (size_t)cc * 16 * DD);
#pragma unroll
    for (int i = tid; i < 1536; i += 256) {
      const int cls = i / 96;       // 96 x short8 per row
      const int d8 = (i % 96) * 8;
      *(short8*)&Bs[cls][d8] = src[i];
    }
    __syncthreads();
    f32x4 acc = {0.f, 0.f, 0.f, 0.f};
#pragma unroll
    for (int kc = 0; kc < 24; kc++) {
      const short8 b = *(const short8*)&Bs[mr][kc * 32 + q * 8];
      acc = __builtin_amdgcn_mfma_f32_16x16x32_bf16(afrag[kc], b, acc, 0, 0, 0);
    }
    vmax[0] = fmaxf(vmax[0], acc[0]);
    vmax[1] = fmaxf(vmax[1], acc[1]);
    vmax[2] = fmaxf(vmax[2], acc[2]);
    vmax[3] = fmaxf(vmax[3], acc[3]);
  }
  // reduce max over the 16 column-lanes of each quad
#pragma unroll
  for (int o = 1; o < 16; o <<= 1) {
#pragma unroll
    for (int r = 0; r < 4; r++) vmax[r] = fmaxf(vmax[r], __shfl_xor(vmax[r], o, 64));
  }
  // rows held by this quad are tokens q*4 + r
  if (mr == 0) {
#pragma unroll
    for (int r = 0; r < 4; r++) {
      const float nr = nrmS[wave][q * 4 + r];
      m_out[tokBase + q * 4 + r] = vmax[r] / fmaxf(sqrtf(nr), 1e-8f);
    }
  }
}

// ---------------------------------------------------------------------------
// Kernel 3: softmax over S per batch. grid = B blocks x 256 threads.
// ---------------------------------------------------------------------------
__global__ __launch_bounds__(256) void k_softmax(const float* __restrict__ m,
                                                 float* __restrict__ beta) {
  const int b = blockIdx.x;
  const int tid = threadIdx.x;
  const float* mb = m + (size_t)b * SS;
  const float v0 = mb[tid];
  const float v1 = mb[tid + 256];
  float mx = fmaxf(v0, v1);
#pragma unroll
  for (int o = 32; o > 0; o >>= 1) mx = fmaxf(mx, __shfl_xor(mx, o, 64));
  __shared__ float wred[4];
  if ((tid & 63) == 0) wred[tid >> 6] = mx;
  __syncthreads();
  mx = fmaxf(fmaxf(wred[0], wred[1]), fmaxf(wred[2], wred[3]));
  const float e0 = __expf(v0 - mx);
  const float e1 = __expf(v1 - mx);
  float s = e0 + e1;
#pragma unroll
  for (int o = 32; o > 0; o >>= 1) s += __shfl_xor(s, o, 64);
  __syncthreads();  // wred reuse hazard
  if ((tid & 63) == 0) wred[tid >> 6] = s;
  __syncthreads();
  s = wred[0] + wred[1] + wred[2] + wred[3];
  const float inv = 1.f / s;
  float* bb = beta + (size_t)b * SS;
  bb[tid] = e0 * inv;
  bb[tid + 256] = e1 * inv;
}

// ---------------------------------------------------------------------------
// Kernel 4: partial z over (batch, s-chunk of 64). grid = 64*8 x 192 threads.
// Thread owns one float4 of D; second (and last) full read of V, coalesced.
// ---------------------------------------------------------------------------
__global__ __launch_bounds__(192) void k_zpart(const float* __restrict__ V,
                                               const float* __restrict__ beta,
                                               float* __restrict__ zpart) {
  const int blk = blockIdx.x;
  const int b = blk >> 3;
  const int sc = blk & 7;
  const int tid = threadIdx.x;
  const float* vb = V + ((size_t)b * SS + sc * 64) * DD + tid * 4;
  const float* bb = beta + (size_t)b * SS + sc * 64;
  float4 acc = {0.f, 0.f, 0.f, 0.f};
  for (int s = 0; s < 64; s++) {
    const float w = bb[s];
    const float4 x = *(const float4*)(vb + (size_t)s * DD);
    acc.x += w * x.x; acc.y += w * x.y; acc.z += w * x.z; acc.w += w * x.w;
  }
  *(float4*)(zpart + (size_t)blk * DD + tid * 4) = acc;
}

// ---------------------------------------------------------------------------
// Kernel 5: reduce 8 z-partials -> z (to out), then out = z @ fc_w^T + fc_b.
// grid = B blocks x 256 threads; fc_w is 1.5 MB -> L2/L3 resident.
// ---------------------------------------------------------------------------
__global__ __launch_bounds__(256) void k_final(const float* __restrict__ zpart,
                                               const float* __restrict__ fc_w,
                                               const float* __restrict__ fc_b,
                                               float* __restrict__ out,
                                               float* __restrict__ zout) {
  const int b = blockIdx.x;
  const int tid = threadIdx.x;
  __shared__ float zs[DD];
  for (int i = tid; i < DD; i += 256) {
    float s = 0.f;
#pragma unroll
    for (int sc = 0; sc < 8; sc++) s += zpart[((size_t)b * 8 + sc) * DD + i];
    zs[i] = s;
    zout[(size_t)b * DD + i] = s;
  }
  __syncthreads();
#pragma unroll
  for (int half = 0; half < 2; half++) {
    const int c = half * 256 + tid;
    const float4* w = (const float4*)(fc_w + (size_t)c * DD);
    float acc = 0.f;
    for (int d4 = 0; d4 < DD / 4; d4++) {
      const float4 ww = w[d4];
      acc += ww.x * zs[d4 * 4] + ww.y * zs[d4 * 4 + 1] +
             ww.z * zs[d4 * 4 + 2] + ww.w * zs[d4 * 4 + 3];
    }
    out[(size_t)b * CC + c] = acc + fc_b[c];
  }
}

// ---------------------------------------------------------------------------
extern "C" void kernel_launch(void* const* d_in, const int* in_sizes, int n_in,
                              void* d_out, int out_size, void* d_ws, size_t ws_size,
                              hipStream_t stream) {
  const float* V  = (const float*)d_in[0];  // [64,512,768]
  const float* L  = (const float*)d_in[1];  // [512,768]
  const float* fw = (const float*)d_in[2];  // [512,768]
  const float* fb = (const float*)d_in[3];  // [512]
  float* out = (float*)d_out;               // [64*512] out, then [64*768] z

  char* ws = (char*)d_ws;
  unsigned short* Lnb = (unsigned short*)ws;            // 786432 B
  float* m     = (float*)(ws + 786432);                 // 131072 B
  float* beta  = (float*)(ws + 786432 + 131072);        // 131072 B
  float* zpart = (float*)(ws + 786432 + 262144);        // 1572864 B (total ~2.5 MB)

  k_label_norm<<<CC, 256, 0, stream>>>(L, Lnb);
  k_sims_max<<<512, 256, 0, stream>>>(V, Lnb, m);
  k_softmax<<<BB, 256, 0, stream>>>(m, beta);
  k_zpart<<<BB * 8, 192, 0, stream>>>(V, beta, zpart);
  k_final<<<BB, 256, 0, stream>>>(zpart, fw, fb, out, out + BB * CC);
}

// Round 2
// 242.758 us; speedup vs baseline: 1.3444x; 1.3444x over previous
//
#include <hip/hip_runtime.h>
#include <cstdint>
#include <cstddef>

// Problem dims (fixed by the reference): B=64, S=512, D=768, C=512
#define BB 64
#define SS 512
#define DD 768
#define CC 512

typedef __attribute__((ext_vector_type(8))) short short8;
typedef __attribute__((ext_vector_type(4))) float f32x4;

#define GLOBAL_AS __attribute__((address_space(1)))
#define LDS_AS __attribute__((address_space(3)))

// float -> bf16 bits, round-to-nearest-even
static __device__ __forceinline__ unsigned short f2bf(float f) {
  union { float f; unsigned u; } v; v.f = f;
  unsigned u = v.u;
  u += 0x7FFFu + ((u >> 16) & 1u);
  return (unsigned short)(u >> 16);
}

// async 16B/lane global->LDS copy (wave-uniform LDS base + lane*16)
static __device__ __forceinline__ void async_copy16(const void* g, void* l) {
  __builtin_amdgcn_global_load_lds((const GLOBAL_AS void*)g, (LDS_AS void*)l,
                                   16, 0, 0);
}

// ---------------------------------------------------------------------------
// Kernel 1: normalize label embeddings -> bf16 rows, XOR-swizzled.
// Row c element d is stored at index ((d>>3) ^ (c&7))*8 + (d&7): 16B chunk j
// goes to slot j^(c&7). Keeps the global row contiguous for global_load_lds
// while making the MFMA-layout ds_read_b128 only 2-way bank-aliased (free).
// ---------------------------------------------------------------------------
__global__ __launch_bounds__(256) void k_label_norm(const float* __restrict__ L,
                                                    unsigned short* __restrict__ Lnb) {
  const int c = blockIdx.x;
  const int tid = threadIdx.x;
  const float* row = L + (size_t)c * DD;
  float v[3];
  float s = 0.f;
#pragma unroll
  for (int k = 0; k < 3; k++) { v[k] = row[tid + 256 * k]; s += v[k] * v[k]; }
#pragma unroll
  for (int o = 32; o > 0; o >>= 1) s += __shfl_xor(s, o, 64);
  __shared__ float wsum[4];
  if ((tid & 63) == 0) wsum[tid >> 6] = s;
  __syncthreads();
  const float tot = wsum[0] + wsum[1] + wsum[2] + wsum[3];
  const float inv = 1.f / fmaxf(sqrtf(tot), 1e-8f);
  unsigned short* orow = Lnb + (size_t)c * DD;
  const int sw = c & 7;
#pragma unroll
  for (int k = 0; k < 3; k++) {
    const int d = tid + 256 * k;
    const int idx = (((d >> 3) ^ sw) << 3) | (d & 7);
    orow[idx] = f2bf(v[k] * inv);
  }
}

// ---------------------------------------------------------------------------
// Kernel 2: m[b,s] = max_c dot(V[b,s,:], Ln[c,:]) / max(||V||,eps)
// 512 blocks x 4 waves x 16 tokens. A-fragments (24 x short8 = 96 VGPR) held
// in registers; V read exactly once. Double-buffered async global_load_lds
// staging of 16-class Lnb chunks (24 KB = 24 x 1KB instructions, 6 per wave);
// prefetch for cc+1 issued before computing cc so the vmcnt(0) drain at the
// barrier is covered by the MFMA phase.
// ---------------------------------------------------------------------------
__global__ __launch_bounds__(256) void k_sims_max(const float* __restrict__ V,
                                                  const unsigned short* __restrict__ Lnb,
                                                  float* __restrict__ m_out) {
  const int tid = threadIdx.x;
  const int wave = tid >> 6;
  const int lane = tid & 63;
  const int q = lane >> 4;    // quad 0..3
  const int mr = lane & 15;   // row (token) for A, col (class) for B
  const int64_t tokBase = (int64_t)blockIdx.x * 64 + wave * 16;

  __shared__ unsigned short Bs[2][16 * DD];  // 2 x 24576 B
  __shared__ float nrmS[4][16];

  // ---- prefetch class-chunk 0 into buf 0 (async, in flight during A load)
  {
    const char* src = (const char*)(Lnb + (size_t)0 * 16 * DD);
    char* dst = (char*)&Bs[0][0];
#pragma unroll
    for (int i = wave; i < 24; i += 4)
      async_copy16(src + i * 1024 + lane * 16, dst + i * 1024);
  }

  // ---- load A fragments + squared norm
  const float* arow = V + (tokBase + mr) * DD + q * 8;
  short8 afrag[24];
  float nrm2 = 0.f;
#pragma unroll
  for (int kc = 0; kc < 24; kc++) {
    const float4* p = (const float4*)(arow + kc * 32);
    const float4 x = p[0];
    const float4 y = p[1];
    short8 a;
    a[0] = (short)f2bf(x.x); a[1] = (short)f2bf(x.y);
    a[2] = (short)f2bf(x.z); a[3] = (short)f2bf(x.w);
    a[4] = (short)f2bf(y.x); a[5] = (short)f2bf(y.y);
    a[6] = (short)f2bf(y.z); a[7] = (short)f2bf(y.w);
    afrag[kc] = a;
    nrm2 += x.x * x.x + x.y * x.y + x.z * x.z + x.w * x.w;
    nrm2 += y.x * y.x + y.y * y.y + y.z * y.z + y.w * y.w;
  }
  // lanes {m, m+16, m+32, m+48} each hold 1/4 of token m's sum of squares
  nrm2 += __shfl_xor(nrm2, 16, 64);
  nrm2 += __shfl_xor(nrm2, 32, 64);
  if (q == 0) nrmS[wave][mr] = nrm2;

  __syncthreads();  // buf0 staged (vmcnt drain) + nrmS visible

  const int sw = mr & 7;  // ds_read swizzle key (row = class index mod 8)
  f32x4 vmax = {-3e38f, -3e38f, -3e38f, -3e38f};
  for (int cc = 0; cc < 32; cc++) {
    const int p = cc & 1;
    // prefetch next chunk into the other buffer (its readers finished at the
    // barrier ending iteration cc-1)
    if (cc + 1 < 32) {
      const char* src = (const char*)(Lnb + (size_t)(cc + 1) * 16 * DD);
      char* dst = (char*)&Bs[p ^ 1][0];
#pragma unroll
      for (int i = wave; i < 24; i += 4)
        async_copy16(src + i * 1024 + lane * 16, dst + i * 1024);
    }
    f32x4 acc = {0.f, 0.f, 0.f, 0.f};
#pragma unroll
    for (int kc = 0; kc < 24; kc++) {
      // chunk (kc*4+q) of row mr lives at slot (kc*4+q)^(mr&7)
      const int off = mr * DD + (((kc << 2) + q) ^ sw) * 8;
      const short8 b = *(const short8*)&Bs[p][off];
      acc = __builtin_amdgcn_mfma_f32_16x16x32_bf16(afrag[kc], b, acc, 0, 0, 0);
    }
    vmax[0] = fmaxf(vmax[0], acc[0]);
    vmax[1] = fmaxf(vmax[1], acc[1]);
    vmax[2] = fmaxf(vmax[2], acc[2]);
    vmax[3] = fmaxf(vmax[3], acc[3]);
    __syncthreads();  // drains prefetch vmcnt + guards buffer reuse
  }
  // reduce max over the 16 column-lanes of each quad
#pragma unroll
  for (int o = 1; o < 16; o <<= 1) {
#pragma unroll
    for (int r = 0; r < 4; r++) vmax[r] = fmaxf(vmax[r], __shfl_xor(vmax[r], o, 64));
  }
  // rows held by this quad are tokens q*4 + r
  if (mr == 0) {
#pragma unroll
    for (int r = 0; r < 4; r++) {
      const float nr = nrmS[wave][q * 4 + r];
      m_out[tokBase + q * 4 + r] = vmax[r] / fmaxf(sqrtf(nr), 1e-8f);
    }
  }
}

// ---------------------------------------------------------------------------
// Kernel 3: softmax over S per batch. grid = B blocks x 256 threads.
// ---------------------------------------------------------------------------
__global__ __launch_bounds__(256) void k_softmax(const float* __restrict__ m,
                                                 float* __restrict__ beta) {
  const int b = blockIdx.x;
  const int tid = threadIdx.x;
  const float* mb = m + (size_t)b * SS;
  const float v0 = mb[tid];
  const float v1 = mb[tid + 256];
  float mx = fmaxf(v0, v1);
#pragma unroll
  for (int o = 32; o > 0; o >>= 1) mx = fmaxf(mx, __shfl_xor(mx, o, 64));
  __shared__ float wred[4];
  if ((tid & 63) == 0) wred[tid >> 6] = mx;
  __syncthreads();
  mx = fmaxf(fmaxf(wred[0], wred[1]), fmaxf(wred[2], wred[3]));
  const float e0 = __expf(v0 - mx);
  const float e1 = __expf(v1 - mx);
  float s = e0 + e1;
#pragma unroll
  for (int o = 32; o > 0; o >>= 1) s += __shfl_xor(s, o, 64);
  __syncthreads();  // wred reuse hazard
  if ((tid & 63) == 0) wred[tid >> 6] = s;
  __syncthreads();
  s = wred[0] + wred[1] + wred[2] + wred[3];
  const float inv = 1.f / s;
  float* bb = beta + (size_t)b * SS;
  bb[tid] = e0 * inv;
  bb[tid + 256] = e1 * inv;
}

// ---------------------------------------------------------------------------
// Kernel 4: partial z over (batch, s-chunk). grid = B*nsc x 192 threads.
// Thread owns one float4 of D; second (and last) full read of V, coalesced.
// ---------------------------------------------------------------------------
__global__ __launch_bounds__(192) void k_zpart(const float* __restrict__ V,
                                               const float* __restrict__ beta,
                                               float* __restrict__ zpart,
                                               int spc, int nsc) {
  const int blk = blockIdx.x;
  const int b = blk / nsc;
  const int sc = blk % nsc;
  const int tid = threadIdx.x;
  const float* vb = V + ((size_t)b * SS + (size_t)sc * spc) * DD + tid * 4;
  const float* bb = beta + (size_t)b * SS + (size_t)sc * spc;
  float4 acc = {0.f, 0.f, 0.f, 0.f};
#pragma unroll 4
  for (int s = 0; s < spc; s++) {
    const float w = bb[s];
    const float4 x = *(const float4*)(vb + (size_t)s * DD);
    acc.x += w * x.x; acc.y += w * x.y; acc.z += w * x.z; acc.w += w * x.w;
  }
  *(float4*)(zpart + (size_t)blk * DD + tid * 4) = acc;
}

// ---------------------------------------------------------------------------
// Kernel 5: reduce z-partials -> z (to out), then out = z @ fc_w^T + fc_b.
// grid = 2*B blocks (b, class-half) x 256 threads; fc_w L2/L3-resident.
// ---------------------------------------------------------------------------
__global__ __launch_bounds__(256) void k_final(const float* __restrict__ zpart,
                                               const float* __restrict__ fc_w,
                                               const float* __restrict__ fc_b,
                                               float* __restrict__ out,
                                               float* __restrict__ zout,
                                               int nsc) {
  const int b = blockIdx.x >> 1;
  const int half = blockIdx.x & 1;
  const int tid = threadIdx.x;
  __shared__ float zs[DD];
  for (int i = tid; i < DD; i += 256) {
    float s = 0.f;
    for (int sc = 0; sc < nsc; sc++) s += zpart[((size_t)b * nsc + sc) * DD + i];
    zs[i] = s;
    if (half == 0) zout[(size_t)b * DD + i] = s;
  }
  __syncthreads();
  const int c = half * 256 + tid;
  const float4* w = (const float4*)(fc_w + (size_t)c * DD);
  float acc = 0.f;
  for (int d4 = 0; d4 < DD / 4; d4++) {
    const float4 ww = w[d4];
    acc += ww.x * zs[d4 * 4] + ww.y * zs[d4 * 4 + 1] +
           ww.z * zs[d4 * 4 + 2] + ww.w * zs[d4 * 4 + 3];
  }
  out[(size_t)b * CC + c] = acc + fc_b[c];
}

// ---------------------------------------------------------------------------
extern "C" void kernel_launch(void* const* d_in, const int* in_sizes, int n_in,
                              void* d_out, int out_size, void* d_ws, size_t ws_size,
                              hipStream_t stream) {
  const float* V  = (const float*)d_in[0];  // [64,512,768]
  const float* L  = (const float*)d_in[1];  // [512,768]
  const float* fw = (const float*)d_in[2];  // [512,768]
  const float* fb = (const float*)d_in[3];  // [512]
  float* out = (float*)d_out;               // [64*512] out, then [64*768] z

  char* ws = (char*)d_ws;
  unsigned short* Lnb = (unsigned short*)ws;            // 786432 B (swizzled)
  float* m     = (float*)(ws + 786432);                 // 131072 B
  float* beta  = (float*)(ws + 917504);                 // 131072 B
  float* zpart = (float*)(ws + 1048576);                // nsc*64*768*4 B

  // 16 s-chunks (4 MB total ws) if the workspace allows, else 8 (2.5 MB)
  const int nsc = (ws_size >= (size_t)1048576 + 16 * BB * DD * 4) ? 16 : 8;
  const int spc = SS / nsc;

  k_label_norm<<<CC, 256, 0, stream>>>(L, Lnb);
  k_sims_max<<<512, 256, 0, stream>>>(V, Lnb, m);
  k_softmax<<<BB, 256, 0, stream>>>(m, beta);
  k_zpart<<<BB * nsc, 192, 0, stream>>>(V, beta, zpart, spc, nsc);
  k_final<<<2 * BB, 256, 0, stream>>>(zpart, fw, fb, out, out + BB * CC, nsc);
}